// Round 10
// baseline (428.111 us; speedup 1.0000x reference)
//
#include <hip/hip_runtime.h>
#include <hip/hip_bf16.h>
#include <hip/hip_fp16.h>

#define NN 100000      // nodes
#define EE 1600000     // edges
#define GG 1024        // graphs
#define NF 9
#define VV 128
#define HH 128
#define LL 3
#define OUTD 10
#define BN_EPS 1e-5f
#define NBUCK 196      // ceil(NN/512) buckets of 512 nodes
#define BCAP 12288     // bucket capacity (avg fill 8192)
#define CHUNK 4096     // edges per split block
#define NSPLIT 391     // ceil(EE/CHUNK)
#define NENC 3125      // NN/32
#define NB128 782      // ceil(NN/128)
// enc block distribution across the 3 CSR-chain dispatches
#define EN1 1100
#define EN2 900
#define EN3 1125       // EN1+EN2+EN3 == NENC

typedef __attribute__((ext_vector_type(8))) short short8;   // 8 bf16 = 4 VGPRs
typedef __attribute__((ext_vector_type(4))) float f32x4;

__device__ inline unsigned short f2bf(float x) {          // RNE f32 -> bf16 bits
    unsigned u = __float_as_uint(x);
    unsigned r = (u + 0x7fffu + ((u >> 16) & 1u)) >> 16;
    return (unsigned short)r;
}
__device__ inline float bf2f(unsigned short b) { return __uint_as_float(((unsigned)b) << 16); }

// 8x v_fma_mix_f32: a[i] += f32(half_i(r)) * nm   (bit-identical to cvt+fmaf)
__device__ inline void mix8(float a[8], const uint4& r, float nm) {
    asm("v_fma_mix_f32 %0, %8, %12, %0 op_sel:[0,0,0] op_sel_hi:[1,0,0]\n\t"
        "v_fma_mix_f32 %1, %8, %12, %1 op_sel:[1,0,0] op_sel_hi:[1,0,0]\n\t"
        "v_fma_mix_f32 %2, %9, %12, %2 op_sel:[0,0,0] op_sel_hi:[1,0,0]\n\t"
        "v_fma_mix_f32 %3, %9, %12, %3 op_sel:[1,0,0] op_sel_hi:[1,0,0]\n\t"
        "v_fma_mix_f32 %4, %10, %12, %4 op_sel:[0,0,0] op_sel_hi:[1,0,0]\n\t"
        "v_fma_mix_f32 %5, %10, %12, %5 op_sel:[1,0,0] op_sel_hi:[1,0,0]\n\t"
        "v_fma_mix_f32 %6, %11, %12, %6 op_sel:[0,0,0] op_sel_hi:[1,0,0]\n\t"
        "v_fma_mix_f32 %7, %11, %12, %7 op_sel:[1,0,0] op_sel_hi:[1,0,0]"
        : "+v"(a[0]), "+v"(a[1]), "+v"(a[2]), "+v"(a[3]),
          "+v"(a[4]), "+v"(a[5]), "+v"(a[6]), "+v"(a[7])
        : "v"(r.x), "v"(r.y), "v"(r.z), "v"(r.w), "v"(nm));
}

// ================= device bodies (shared by fused dispatches) =================

// ---- atom encoder + MFMA @ W0 for node block `encblk` (row-major hw out) ----
__device__ void enc_body(char* smem_raw, int tid, int encblk,
        const int* __restrict__ x, const float* __restrict__ emb,
        const unsigned short* __restrict__ WThi, const unsigned short* __restrict__ WTlo,
        __half* __restrict__ hw_out) {
    unsigned short (*lh)[136] = (unsigned short(*)[136])smem_raw;
    unsigned short (*ll)[136] = (unsigned short(*)[136])(smem_raw + 32 * 136 * 2);
    int nloc = tid >> 3;           // 0..31
    int seg = tid & 7;             // 16-ch segment
    int nodebase = encblk * 32;
    int n = nodebase + nloc;
    float s[16];
#pragma unroll
    for (int i = 0; i < 16; ++i) s[i] = 0.f;
#pragma unroll
    for (int f = 0; f < NF; ++f) {
        int idx = x[n * NF + f];
        const float4* ep = (const float4*)(emb + ((size_t)(f * VV + idx)) * HH + seg * 16);
#pragma unroll
        for (int q = 0; q < 4; ++q) {
            float4 e = ep[q];
            s[q * 4 + 0] += e.x; s[q * 4 + 1] += e.y;
            s[q * 4 + 2] += e.z; s[q * 4 + 3] += e.w;
        }
    }
#pragma unroll
    for (int q = 0; q < 4; ++q) {
        ushort4 oh, ol;
        oh.x = f2bf(s[q * 4 + 0]); ol.x = f2bf(s[q * 4 + 0] - bf2f(oh.x));
        oh.y = f2bf(s[q * 4 + 1]); ol.y = f2bf(s[q * 4 + 1] - bf2f(oh.y));
        oh.z = f2bf(s[q * 4 + 2]); ol.z = f2bf(s[q * 4 + 2] - bf2f(oh.z));
        oh.w = f2bf(s[q * 4 + 3]); ol.w = f2bf(s[q * 4 + 3] - bf2f(oh.w));
        *(ushort4*)&lh[nloc][seg * 16 + q * 4] = oh;
        *(ushort4*)&ll[nloc][seg * 16 + q * 4] = ol;
    }
    __syncthreads();
    int wave = tid >> 6, lane = tid & 63;
    int quad = lane >> 4, m = lane & 15;
    f32x4 acc[2][2] = {};
    int kq = quad * 8;
#pragma unroll
    for (int t = 0; t < 4; ++t) {
        int k0 = t * 32 + kq;
        short8 a0h = *(const short8*)&lh[m][k0];
        short8 a0l = *(const short8*)&ll[m][k0];
        short8 a1h = *(const short8*)&lh[16 + m][k0];
        short8 a1l = *(const short8*)&ll[16 + m][k0];
#pragma unroll
        for (int c = 0; c < 2; ++c) {
            int ct = wave * 2 + c;
            short8 bh = *(const short8*)(WThi + (size_t)(ct * 16 + m) * HH + k0);
            short8 bl = *(const short8*)(WTlo + (size_t)(ct * 16 + m) * HH + k0);
            acc[0][c] = __builtin_amdgcn_mfma_f32_16x16x32_bf16(a0h, bh, acc[0][c], 0, 0, 0);
            acc[0][c] = __builtin_amdgcn_mfma_f32_16x16x32_bf16(a0l, bh, acc[0][c], 0, 0, 0);
            acc[0][c] = __builtin_amdgcn_mfma_f32_16x16x32_bf16(a0h, bl, acc[0][c], 0, 0, 0);
            acc[1][c] = __builtin_amdgcn_mfma_f32_16x16x32_bf16(a1h, bh, acc[1][c], 0, 0, 0);
            acc[1][c] = __builtin_amdgcn_mfma_f32_16x16x32_bf16(a1l, bh, acc[1][c], 0, 0, 0);
            acc[1][c] = __builtin_amdgcn_mfma_f32_16x16x32_bf16(a1h, bl, acc[1][c], 0, 0, 0);
        }
    }
#pragma unroll
    for (int c = 0; c < 2; ++c) {
        int colx = (wave * 2 + c) * 16 + m;
#pragma unroll
        for (int rt = 0; rt < 2; ++rt) {
            int r0 = nodebase + rt * 16 + quad * 4;
#pragma unroll
            for (int reg = 0; reg < 4; ++reg)
                hw_out[(size_t)(r0 + reg) * HH + colx] = __float2half(acc[rt][c][reg]);
        }
    }
}

// ================= CSR-chain kernels, each carrying a slab of enc blocks =====

__global__ __launch_bounds__(256) void split_enc_kernel(
        const int* __restrict__ src, const int* __restrict__ dst,
        int* __restrict__ bcur, int* __restrict__ bucket_edges,
        const int* __restrict__ x, const float* __restrict__ emb,
        const unsigned short* __restrict__ WThi, const unsigned short* __restrict__ WTlo,
        __half* __restrict__ hw_out) {
    __shared__ __align__(16) char smem_raw[25600];
    int tid = threadIdx.x;
    if (blockIdx.x >= NSPLIT) {
        enc_body(smem_raw, tid, blockIdx.x - NSPLIT, x, emb, WThi, WTlo, hw_out);
        return;
    }
    int* lcnt  = (int*)smem_raw;
    int* loff  = lcnt + 256;
    int* lcur  = loff + 256;
    int* gbase = lcur + 256;
    int* sh    = gbase + 256;
    int* stage = sh + 256;
    unsigned char* stageb = (unsigned char*)(stage + CHUNK);
    int cs = blockIdx.x * CHUNK;
    int n = min(CHUNK, EE - cs);
    lcnt[tid] = 0;
    __syncthreads();
    for (int i = tid; i < n; i += 256)
        atomicAdd(&lcnt[dst[cs + i] >> 9], 1);
    __syncthreads();
    int val = lcnt[tid];
    sh[tid] = val; __syncthreads();
    for (int d = 1; d < 256; d <<= 1) {
        int t = (tid >= d) ? sh[tid - d] : 0;
        __syncthreads();
        sh[tid] += t;
        __syncthreads();
    }
    loff[tid] = sh[tid] - val;
    lcur[tid] = sh[tid] - val;
    __syncthreads();
    for (int i = tid; i < n; i += 256) {
        int d = dst[cs + i], s = src[cs + i];
        int b = d >> 9;
        int p = atomicAdd(&lcur[b], 1);
        stage[p] = (s << 9) | (d & 511);
        stageb[p] = (unsigned char)b;
    }
    if (val > 0) gbase[tid] = atomicAdd(&bcur[tid], val);
    __syncthreads();
    for (int i = tid; i < n; i += 256) {
        int b = stageb[i];
        bucket_edges[(size_t)b * BCAP + gbase[b] + (i - loff[b])] = stage[i];
    }
}

__global__ __launch_bounds__(256) void bhist_enc_kernel(const int* __restrict__ bcur,
        const int* __restrict__ bucket_edges,
        int* __restrict__ cnt, float* __restrict__ dinv, int* __restrict__ bsum,
        const int* __restrict__ x, const float* __restrict__ emb,
        const unsigned short* __restrict__ WThi, const unsigned short* __restrict__ WTlo,
        __half* __restrict__ hw_out) {
    __shared__ __align__(16) char smem_raw[17408];
    int tid = threadIdx.x;
    if (blockIdx.x >= NBUCK) {
        enc_body(smem_raw, tid, EN1 + (blockIdx.x - NBUCK), x, emb, WThi, WTlo, hw_out);
        return;
    }
    int* lc = (int*)smem_raw;          // 512 ints
    int* sh = lc + 512;                // 256 ints
    int b = blockIdx.x;
    lc[tid] = 0; lc[tid + 256] = 0;
    __syncthreads();
    int n = bcur[b];
    const int* be = bucket_edges + (size_t)b * BCAP;
    for (int i = tid; i < n; i += 256) atomicAdd(&lc[be[i] & 511], 1);
    __syncthreads();
    int node = b * 512 + tid;
    int c0 = lc[tid], c1 = lc[tid + 256];
    int s = 0;
    if (node < NN) { cnt[node] = c0; dinv[node] = rsqrtf(1.0f + (float)c0); s += c0; }
    if (node + 256 < NN) { cnt[node + 256] = c1; dinv[node + 256] = rsqrtf(1.0f + (float)c1); s += c1; }
    sh[tid] = s; __syncthreads();
    for (int d = 128; d > 0; d >>= 1) { if (tid < d) sh[tid] += sh[tid + d]; __syncthreads(); }
    if (tid == 0) bsum[b] = sh[0];
}

// ---- merged node-scan + CSR scatter: block b serves bucket b end-to-end ----
// scanC's per-bucket row_ptr values are exactly the cursors cscatter needs, so
// they stay in LDS; row_ptr is still written for the agg kernels.
__global__ __launch_bounds__(256) void scan_scatter_enc_kernel(const int* __restrict__ cnt,
        const int* __restrict__ bsum, int* __restrict__ row_ptr,
        const int* __restrict__ bcur, const int* __restrict__ bucket_edges,
        const float* __restrict__ dinv, int2* __restrict__ col,
        const int* __restrict__ x, const float* __restrict__ emb,
        const unsigned short* __restrict__ WThi, const unsigned short* __restrict__ WTlo,
        __half* __restrict__ hw_out) {
    __shared__ __align__(16) char smem_raw[17408];
    int tid = threadIdx.x;
    if (blockIdx.x >= NBUCK) {
        enc_body(smem_raw, tid, EN1 + EN2 + (blockIdx.x - NBUCK), x, emb, WThi, WTlo, hw_out);
        return;
    }
    int* sh   = (int*)smem_raw;        // 256 ints
    int* pre  = sh + 256;              // 256 ints
    int* lcur = pre + 256;             // 512 ints
    int b = blockIdx.x;
    pre[tid] = (tid < b) ? bsum[tid] : 0;   // b <= 195 < 256
    __syncthreads();
    for (int d = 128; d > 0; d >>= 1) { if (tid < d) pre[tid] += pre[tid + d]; __syncthreads(); }
    int bbase = pre[0];
    int base = b * 512 + tid * 2;
    int v0 = (base < NN) ? cnt[base] : 0;
    int v1 = (base + 1 < NN) ? cnt[base + 1] : 0;
    int ts = v0 + v1;
    sh[tid] = ts; __syncthreads();
    for (int d = 1; d < 256; d <<= 1) {
        int t = (tid >= d) ? sh[tid - d] : 0;
        __syncthreads();
        sh[tid] += t;
        __syncthreads();
    }
    int excl = sh[tid] - ts + bbase;
    if (base < NN) row_ptr[base] = excl;
    if (base + 1 < NN) row_ptr[base + 1] = excl + v0;
    lcur[tid * 2] = excl;
    lcur[tid * 2 + 1] = excl + v0;
    if (b == 0 && tid == 0) row_ptr[NN] = EE;
    __syncthreads();
    // scatter
    int node0 = b * 512;
    int n = bcur[b];
    const int* be = bucket_edges + (size_t)b * BCAP;
    for (int i = tid; i < n; i += 256) {
        int w = be[i];
        int j = w & 511;
        int s = (int)((unsigned)w >> 9);
        int p = atomicAdd(&lcur[j], 1);
        float nm = dinv[s] * dinv[node0 + j];
        col[p] = make_int2(s, __float_as_int(nm));
    }
}

// ---------------- W^T conversion + classifier prep + clears + graph counts ----------------
__global__ __launch_bounds__(256) void wprep_kernel(const float* __restrict__ Ws,
        const float* __restrict__ Wc, const float* __restrict__ b2,
        const int* __restrict__ batch,
        unsigned short* __restrict__ WThi, unsigned short* __restrict__ WTlo,
        unsigned short* __restrict__ WcThi, unsigned short* __restrict__ WcTlo,
        float* __restrict__ bb2, int* __restrict__ bcur, float* __restrict__ pooled,
        int* __restrict__ gcnt, int* __restrict__ ctr) {
    int id = blockIdx.x * 256 + threadIdx.x;
    if (id < LL * HH * HH) {
        int layer = id >> 14;
        int rem = id & (HH * HH - 1);
        int k = rem >> 7, n = rem & 127;
        float w = Ws[id];
        unsigned short hi = f2bf(w);
        float lo = w - bf2f(hi);
        WThi[(size_t)layer * HH * HH + n * HH + k] = hi;   // transposed: [n][k]
        WTlo[(size_t)layer * HH * HH + n * HH + k] = f2bf(lo);
    }
    int tid = threadIdx.x;
    if (blockIdx.x == 0) {
        const float* W2 = Ws + (size_t)2 * HH * HH;        // layer-2 weight [k][j]
        for (int i = tid; i < 16 * HH; i += 256) {
            int n = i >> 7, k = i & 127;
            float s = 0.f;
            if (n < OUTD) {
                for (int j = 0; j < HH; ++j)
                    s += W2[k * HH + j] * Wc[j * OUTD + n];   // Wfused[k][n]
            }
            unsigned short hi = f2bf(s);
            WcThi[i] = hi;                 // [n][k] transposed
            WcTlo[i] = f2bf(s - bf2f(hi));
        }
        if (tid < OUTD) {
            float s = 0.f;
            for (int c = 0; c < HH; ++c) s += b2[c] * Wc[c * OUTD + tid];
            bb2[tid] = s;
        }
    } else if (blockIdx.x == 1) {
        bcur[tid] = 0;
        if (tid == 0) *ctr = 0;
    } else if (blockIdx.x >= 2 && blockIdx.x < 66) {
        pooled[(blockIdx.x - 2) * 256 + tid] = 0.f;        // GG*16 = 64*256
    } else if (blockIdx.x >= 66 && blockIdx.x < 70) {
        int g = (blockIdx.x - 66) * 256 + tid;             // 0..1023
        int lo = 0, hi = NN;
        while (lo < hi) { int mid = (lo + hi) >> 1; if (batch[mid] < g) lo = mid + 1; else hi = mid; }
        int s0 = lo;
        lo = 0; hi = NN;
        int g1 = g + 1;
        while (lo < hi) { int mid = (lo + hi) >> 1; if (batch[mid] < g1) lo = mid + 1; else hi = mid; }
        gcnt[g] = lo - s0;
    }
}

// ---------------- Gather core: one 16-lane group per node (128-ch rows) ----------------
__device__ inline void gather_node(const uint4* __restrict__ hw4,
                                   const int2* __restrict__ col,
                                   int start, int end, int c4,
                                   float a[8], float b[8]) {
    int e = start;
    for (; e + 4 <= end; e += 4) {
        unsigned long long w0 = *(const unsigned long long*)&col[e];
        unsigned long long w1 = *(const unsigned long long*)&col[e + 1];
        unsigned long long w2 = *(const unsigned long long*)&col[e + 2];
        unsigned long long w3 = *(const unsigned long long*)&col[e + 3];
        uint4 r0 = hw4[(size_t)(unsigned)(w0 & 0xffffffffu) * 16 + c4];
        uint4 r1 = hw4[(size_t)(unsigned)(w1 & 0xffffffffu) * 16 + c4];
        uint4 r2 = hw4[(size_t)(unsigned)(w2 & 0xffffffffu) * 16 + c4];
        uint4 r3 = hw4[(size_t)(unsigned)(w3 & 0xffffffffu) * 16 + c4];
        mix8(a, r0, __int_as_float((int)(unsigned)(w0 >> 32)));
        mix8(b, r1, __int_as_float((int)(unsigned)(w1 >> 32)));
        mix8(a, r2, __int_as_float((int)(unsigned)(w2 >> 32)));
        mix8(b, r3, __int_as_float((int)(unsigned)(w3 >> 32)));
    }
    if (e < end) {
        int last = end - 1;
        int e1 = min(e + 1, last), e2 = min(e + 2, last), e3 = min(e + 3, last);
        unsigned long long w0 = *(const unsigned long long*)&col[e];
        unsigned long long w1 = *(const unsigned long long*)&col[e1];
        unsigned long long w2 = *(const unsigned long long*)&col[e2];
        unsigned long long w3 = *(const unsigned long long*)&col[e3];
        float n0 = __int_as_float((int)(unsigned)(w0 >> 32));
        float n1 = (e + 1 < end) ? __int_as_float((int)(unsigned)(w1 >> 32)) : 0.f;
        float n2 = (e + 2 < end) ? __int_as_float((int)(unsigned)(w2 >> 32)) : 0.f;
        float n3 = (e + 3 < end) ? __int_as_float((int)(unsigned)(w3 >> 32)) : 0.f;
        uint4 r0 = hw4[(size_t)(unsigned)(w0 & 0xffffffffu) * 16 + c4];
        uint4 r1 = hw4[(size_t)(unsigned)(w1 & 0xffffffffu) * 16 + c4];
        uint4 r2 = hw4[(size_t)(unsigned)(w2 & 0xffffffffu) * 16 + c4];
        uint4 r3 = hw4[(size_t)(unsigned)(w3 & 0xffffffffu) * 16 + c4];
        mix8(a, r0, n0);
        mix8(b, r1, n1);
        mix8(a, r2, n2);
        mix8(b, r3, n3);
    }
}

// ---------------- Fused: CSR aggregate + bias + BN + ReLU -> LDS -> MFMA ----------------
template<bool DO_PROJ>
__global__ __launch_bounds__(512) void agg_mm_kernel(const __half* __restrict__ hw_in,
    const int* __restrict__ row_ptr, const int2* __restrict__ col,
    const float* __restrict__ dinv,
    const float* __restrict__ bias, const float* __restrict__ gamma,
    const float* __restrict__ beta, const float* __restrict__ rmean,
    const float* __restrict__ rvar,
    const unsigned short* __restrict__ WThi, const unsigned short* __restrict__ WTlo,
    __half* __restrict__ hw_out,
    const unsigned short* __restrict__ WcThi, const unsigned short* __restrict__ WcTlo,
    __half* __restrict__ y_out) {
    __shared__ __align__(16) unsigned short lh[32][136];
    __shared__ __align__(16) unsigned short ll[32][136];
    int wave = threadIdx.x >> 6;     // 0..7
    int lane = threadIdx.x & 63;
    int grp = lane >> 4;             // 0..3 : node within wave
    int c4 = lane & 15;              // 16B chunk within row
    int nodebase = blockIdx.x * 32;
    const uint4* hw4 = (const uint4*)hw_in;

    int v = nodebase + wave * 4 + grp;
    int start = row_ptr[v], end = row_ptr[v + 1];
    float a[8] = {}, b[8] = {};
    gather_node(hw4, col, start, end, c4, a, b);

    // self-loop term
    {
        float dv = dinv[v];
        uint4 r = hw4[(size_t)v * 16 + c4];
        mix8(a, r, dv * dv);
    }
#pragma unroll
    for (int i = 0; i < 8; ++i) a[i] += b[i];

    int ch = c4 * 8;
#pragma unroll
    for (int i = 0; i < 8; ++i) a[i] += bias[ch + i];
#pragma unroll
    for (int i = 0; i < 8; ++i) {
        int c = ch + i;
        float sc = gamma[c] * rsqrtf(rvar[c] + BN_EPS);
        a[i] = fmaxf((a[i] - rmean[c]) * sc + beta[c], 0.f);
    }
    int rloc = wave * 4 + grp;
    ushort4 oh0, oh1, ol0, ol1;
    oh0.x = f2bf(a[0]); ol0.x = f2bf(a[0] - bf2f(oh0.x));
    oh0.y = f2bf(a[1]); ol0.y = f2bf(a[1] - bf2f(oh0.y));
    oh0.z = f2bf(a[2]); ol0.z = f2bf(a[2] - bf2f(oh0.z));
    oh0.w = f2bf(a[3]); ol0.w = f2bf(a[3] - bf2f(oh0.w));
    oh1.x = f2bf(a[4]); ol1.x = f2bf(a[4] - bf2f(oh1.x));
    oh1.y = f2bf(a[5]); ol1.y = f2bf(a[5] - bf2f(oh1.y));
    oh1.z = f2bf(a[6]); ol1.z = f2bf(a[6] - bf2f(oh1.z));
    oh1.w = f2bf(a[7]); ol1.w = f2bf(a[7] - bf2f(oh1.w));
    *(ushort4*)&lh[rloc][ch]     = oh0;
    *(ushort4*)&lh[rloc][ch + 4] = oh1;
    *(ushort4*)&ll[rloc][ch]     = ol0;
    *(ushort4*)&ll[rloc][ch + 4] = ol1;

    __syncthreads();
    int quad = lane >> 4, m = lane & 15;
    int kq = quad * 8;
    if constexpr (!DO_PROJ) {
        f32x4 acc[2] = {};
        int ct = wave;                   // 1 column-tile per wave
#pragma unroll
        for (int t = 0; t < 4; ++t) {
            int k0 = t * 32 + kq;
            short8 a0h = *(const short8*)&lh[m][k0];
            short8 a0l = *(const short8*)&ll[m][k0];
            short8 a1h = *(const short8*)&lh[16 + m][k0];
            short8 a1l = *(const short8*)&ll[16 + m][k0];
            short8 bh = *(const short8*)(WThi + (size_t)(ct * 16 + m) * HH + k0);
            short8 bl = *(const short8*)(WTlo + (size_t)(ct * 16 + m) * HH + k0);
            acc[0] = __builtin_amdgcn_mfma_f32_16x16x32_bf16(a0h, bh, acc[0], 0, 0, 0);
            acc[0] = __builtin_amdgcn_mfma_f32_16x16x32_bf16(a0l, bh, acc[0], 0, 0, 0);
            acc[0] = __builtin_amdgcn_mfma_f32_16x16x32_bf16(a0h, bl, acc[0], 0, 0, 0);
            acc[1] = __builtin_amdgcn_mfma_f32_16x16x32_bf16(a1h, bh, acc[1], 0, 0, 0);
            acc[1] = __builtin_amdgcn_mfma_f32_16x16x32_bf16(a1l, bh, acc[1], 0, 0, 0);
            acc[1] = __builtin_amdgcn_mfma_f32_16x16x32_bf16(a1h, bl, acc[1], 0, 0, 0);
        }
        int colx = ct * 16 + m;
#pragma unroll
        for (int rt = 0; rt < 2; ++rt) {
            int r0 = nodebase + rt * 16 + quad * 4;
#pragma unroll
            for (int reg = 0; reg < 4; ++reg)
                hw_out[(size_t)(r0 + reg) * HH + colx] = __float2half(acc[rt][reg]);
        }
    } else {
        // y = h2_rows @ Wfused^T : waves 0,1 handle row-tiles 0,1; cols 0-15
        if (wave < 2) {
            f32x4 pacc = {};
#pragma unroll
            for (int t = 0; t < 4; ++t) {
                int k0 = t * 32 + kq;
                short8 ah = *(const short8*)&lh[wave * 16 + m][k0];
                short8 al = *(const short8*)&ll[wave * 16 + m][k0];
                short8 bh = *(const short8*)(WcThi + (size_t)m * HH + k0);
                short8 bl = *(const short8*)(WcTlo + (size_t)m * HH + k0);
                pacc = __builtin_amdgcn_mfma_f32_16x16x32_bf16(ah, bh, pacc, 0, 0, 0);
                pacc = __builtin_amdgcn_mfma_f32_16x16x32_bf16(al, bh, pacc, 0, 0, 0);
                pacc = __builtin_amdgcn_mfma_f32_16x16x32_bf16(ah, bl, pacc, 0, 0, 0);
            }
#pragma unroll
            for (int reg = 0; reg < 4; ++reg) {
                int node = nodebase + wave * 16 + quad * 4 + reg;
                y_out[(size_t)node * 16 + m] = __float2half(pacc[reg]);
            }
        }
    }
}

// ---------------- Last aggregate on 16-ch f16 y + pooling + tail-block finalize ----------------
__global__ __launch_bounds__(256) void agg_pool_kernel(const __half* __restrict__ y,
    const int* __restrict__ row_ptr, const int2* __restrict__ col,
    const float* __restrict__ dinv, const int* __restrict__ batch,
    float* __restrict__ pooled,
    const int* __restrict__ gcnt, const float* __restrict__ bb2,
    const float* __restrict__ bc, float* __restrict__ out, int* __restrict__ ctr) {
    __shared__ __align__(16) float lz[128][16];
    __shared__ int bg[128];
    __shared__ int is_last;
    int tid = threadIdx.x;
    int g2 = tid >> 1;               // node slot 0..127
    int cl = tid & 1;                // 16B half of row
    int nodebase = blockIdx.x * 128;
    int v = nodebase + g2;
    int vc = min(v, NN - 1);
    int start = row_ptr[vc];
    int end = (v < NN) ? row_ptr[vc + 1] : start;
    const uint4* y4 = (const uint4*)y;   // row = 2 x uint4 (16 halves)
    float a[8] = {};
    int e = start;
    for (; e + 4 <= end; e += 4) {
        unsigned long long w0 = *(const unsigned long long*)&col[e];
        unsigned long long w1 = *(const unsigned long long*)&col[e + 1];
        unsigned long long w2 = *(const unsigned long long*)&col[e + 2];
        unsigned long long w3 = *(const unsigned long long*)&col[e + 3];
        uint4 r0 = y4[(size_t)(unsigned)(w0 & 0xffffffffu) * 2 + cl];
        uint4 r1 = y4[(size_t)(unsigned)(w1 & 0xffffffffu) * 2 + cl];
        uint4 r2 = y4[(size_t)(unsigned)(w2 & 0xffffffffu) * 2 + cl];
        uint4 r3 = y4[(size_t)(unsigned)(w3 & 0xffffffffu) * 2 + cl];
        mix8(a, r0, __int_as_float((int)(unsigned)(w0 >> 32)));
        mix8(a, r1, __int_as_float((int)(unsigned)(w1 >> 32)));
        mix8(a, r2, __int_as_float((int)(unsigned)(w2 >> 32)));
        mix8(a, r3, __int_as_float((int)(unsigned)(w3 >> 32)));
    }
    if (e < end) {
        int last = end - 1;
        int e1 = min(e + 1, last), e2 = min(e + 2, last), e3 = min(e + 3, last);
        unsigned long long w0 = *(const unsigned long long*)&col[e];
        unsigned long long w1 = *(const unsigned long long*)&col[e1];
        unsigned long long w2 = *(const unsigned long long*)&col[e2];
        unsigned long long w3 = *(const unsigned long long*)&col[e3];
        float n0 = __int_as_float((int)(unsigned)(w0 >> 32));
        float n1 = (e + 1 < end) ? __int_as_float((int)(unsigned)(w1 >> 32)) : 0.f;
        float n2 = (e + 2 < end) ? __int_as_float((int)(unsigned)(w2 >> 32)) : 0.f;
        float n3 = (e + 3 < end) ? __int_as_float((int)(unsigned)(w3 >> 32)) : 0.f;
        uint4 r0 = y4[(size_t)(unsigned)(w0 & 0xffffffffu) * 2 + cl];
        uint4 r1 = y4[(size_t)(unsigned)(w1 & 0xffffffffu) * 2 + cl];
        uint4 r2 = y4[(size_t)(unsigned)(w2 & 0xffffffffu) * 2 + cl];
        uint4 r3 = y4[(size_t)(unsigned)(w3 & 0xffffffffu) * 2 + cl];
        mix8(a, r0, n0);
        mix8(a, r1, n1);
        mix8(a, r2, n2);
        mix8(a, r3, n3);
    }
    if (v < NN) {
        float dv = dinv[v];
        uint4 r = y4[(size_t)v * 2 + cl];
        mix8(a, r, dv * dv);
    } else {
#pragma unroll
        for (int i = 0; i < 8; ++i) a[i] = 0.f;
    }
    int chb = cl * 8;
#pragma unroll
    for (int i = 0; i < 8; ++i) lz[g2][chb + i] = a[i];
    if (cl == 0) bg[g2] = batch[vc];
    __syncthreads();
    // pooling partials: 256 threads = 16 ch x 16 row-groups of 8
    int ch = tid & 15;
    int rh = tid >> 4;               // 0..15
    int r0i = rh * 8;
    int curg = bg[r0i];
    float run = 0.f;
    for (int r = r0i; r < r0i + 8; ++r) {
        int gg = bg[r];
        if (gg != curg) {
            atomicAdd(&pooled[(size_t)curg * 16 + ch], run);
            run = 0.f; curg = gg;
        }
        run += lz[r][ch];
    }
    atomicAdd(&pooled[(size_t)curg * 16 + ch], run);

    // tail-block finalize (replaces the finalize dispatch)
    __threadfence();
    __syncthreads();
    if (tid == 0) is_last = (atomicAdd(ctr, 1) == (int)gridDim.x - 1);
    __syncthreads();
    if (is_last) {
        for (int id = tid; id < GG * OUTD; id += 256) {
            int g = id / OUTD, o = id - g * OUTD;
            int cg = gcnt[g];
            // read pooled at the same coherence point the writers used
            float pv = atomicAdd(&pooled[(size_t)g * 16 + o], 0.0f);
            out[(size_t)g * OUTD + o] = pv / fmaxf((float)cg, 1.0f)
                                        + ((cg > 0) ? bb2[o] : 0.f) + bc[o];
        }
    }
}

extern "C" void kernel_launch(void* const* d_in, const int* in_sizes, int n_in,
                              void* d_out, int out_size, void* d_ws, size_t ws_size,
                              hipStream_t stream) {
    const int*   x      = (const int*)d_in[0];
    const int*   eidx   = (const int*)d_in[1];
    const int*   batch  = (const int*)d_in[2];
    const float* emb    = (const float*)d_in[3];
    const float* Ws     = (const float*)d_in[4];
    const float* bs     = (const float*)d_in[5];
    const float* gamma  = (const float*)d_in[6];
    const float* beta   = (const float*)d_in[7];
    const float* rmean  = (const float*)d_in[8];
    const float* rvar   = (const float*)d_in[9];
    const float* Wclf   = (const float*)d_in[10];
    const float* bclf   = (const float*)d_in[11];
    float* out = (float*)d_out;

    const int* e_src = eidx;
    const int* e_dst = eidx + EE;

    char* ws = (char*)d_ws;
    size_t off = 0;
    auto take = [&](size_t bytes) -> void* {
        void* p = ws + off;
        off = (off + bytes + 255) & ~(size_t)255;
        return p;
    };
    float* dinv     = (float*)take((size_t)NN * 4);
    int*   cnt      = (int*)  take((size_t)NN * 4);
    int*   row_ptr  = (int*)  take((size_t)(NN + 1) * 4);
    int*   bsum     = (int*)  take((size_t)NBUCK * 4);
    int*   bcur     = (int*)  take((size_t)256 * 4);
    int*   gcnt     = (int*)  take((size_t)GG * 4);
    int*   ctr      = (int*)  take((size_t)4);
    int*   bucket_edges = (int*)take((size_t)NBUCK * BCAP * 4);
    int2*  col      = (int2*) take((size_t)EE * 8 + 64);   // +64B safety pad
    __half* hwA     = (__half*)take((size_t)NN * HH * 2);
    __half* hwB     = (__half*)take((size_t)NN * HH * 2);
    __half* yh      = (__half*)take((size_t)NN * 16 * 2);
    float* pooled   = (float*)take((size_t)GG * 16 * 4);
    unsigned short* WThi = (unsigned short*)take((size_t)LL * HH * HH * 2);
    unsigned short* WTlo = (unsigned short*)take((size_t)LL * HH * HH * 2);
    unsigned short* WcThi = (unsigned short*)take((size_t)16 * HH * 2);
    unsigned short* WcTlo = (unsigned short*)take((size_t)16 * HH * 2);
    float* bb2      = (float*)take((size_t)16 * 4);

    // weight prep + buffer clears + graph counts (absorbs memsets + old finalize searches)
    wprep_kernel<<<(LL * HH * HH + 255) / 256, 256, 0, stream>>>(Ws, Wclf, bs + 2 * HH,
        batch, WThi, WTlo, WcThi, WcTlo, bb2, bcur, pooled, gcnt, ctr);
    // CSR chain with enc blocks spread across all three dispatches:
    split_enc_kernel<<<NSPLIT + EN1, 256, 0, stream>>>(e_src, e_dst, bcur, bucket_edges,
        x, emb, WThi, WTlo, hwA);
    bhist_enc_kernel<<<NBUCK + EN2, 256, 0, stream>>>(bcur, bucket_edges, cnt, dinv, bsum,
        x, emb, WThi, WTlo, hwA);
    scan_scatter_enc_kernel<<<NBUCK + EN3, 256, 0, stream>>>(cnt, bsum, row_ptr,
        bcur, bucket_edges, dinv, col,
        x, emb, WThi, WTlo, hwA);

    // layer 0: agg(hw1)+bias0+BN0+ReLU -> LDS -> @ W1 -> hw2
    agg_mm_kernel<false><<<NN / 32, 512, 0, stream>>>(hwA, row_ptr, col, dinv,
        bs, gamma, beta, rmean, rvar,
        WThi + (size_t)1 * HH * HH, WTlo + (size_t)1 * HH * HH, hwB,
        nullptr, nullptr, nullptr);
    // layer 1: agg(hw2)+bias1+BN1+ReLU -> y = h2 @ (W2@Wc) only
    agg_mm_kernel<true><<<NN / 32, 512, 0, stream>>>(hwB, row_ptr, col, dinv,
        bs + HH, gamma + HH, beta + HH, rmean + HH, rvar + HH,
        nullptr, nullptr, nullptr,
        WcThi, WcTlo, yh);
    // layer 2 aggregate on 16-ch f16 y + pooling + tail-block finalize
    agg_pool_kernel<<<NB128, 256, 0, stream>>>(yh, row_ptr, col, dinv, batch, pooled,
        gcnt, bb2, bclf, out, ctr);
}

// Round 11
// 365.759 us; speedup vs baseline: 1.1705x; 1.1705x over previous
//
#include <hip/hip_runtime.h>
#include <hip/hip_bf16.h>
#include <hip/hip_fp16.h>

#define NN 100000      // nodes
#define EE 1600000     // edges
#define GG 1024        // graphs
#define NF 9
#define VV 128
#define HH 128
#define LL 3
#define OUTD 10
#define BN_EPS 1e-5f
#define NBUCK 196      // ceil(NN/512) buckets of 512 nodes
#define BCAP 12288     // bucket capacity (avg fill 8192)
#define CHUNK 4096     // edges per split block
#define NSPLIT 391     // ceil(EE/CHUNK)
#define NENC 3125      // NN/32
#define NB128 782      // ceil(NN/128)
// enc block distribution across the 3 CSR-chain dispatches
#define EN1 1100
#define EN2 900
#define EN3 1125       // EN1+EN2+EN3 == NENC

typedef __attribute__((ext_vector_type(8))) short short8;   // 8 bf16 = 4 VGPRs
typedef __attribute__((ext_vector_type(4))) float f32x4;

__device__ inline unsigned short f2bf(float x) {          // RNE f32 -> bf16 bits
    unsigned u = __float_as_uint(x);
    unsigned r = (u + 0x7fffu + ((u >> 16) & 1u)) >> 16;
    return (unsigned short)r;
}
__device__ inline float bf2f(unsigned short b) { return __uint_as_float(((unsigned)b) << 16); }

// 8x v_fma_mix_f32: a[i] += f32(half_i(r)) * nm   (bit-identical to cvt+fmaf)
__device__ inline void mix8(float a[8], const uint4& r, float nm) {
    asm("v_fma_mix_f32 %0, %8, %12, %0 op_sel:[0,0,0] op_sel_hi:[1,0,0]\n\t"
        "v_fma_mix_f32 %1, %8, %12, %1 op_sel:[1,0,0] op_sel_hi:[1,0,0]\n\t"
        "v_fma_mix_f32 %2, %9, %12, %2 op_sel:[0,0,0] op_sel_hi:[1,0,0]\n\t"
        "v_fma_mix_f32 %3, %9, %12, %3 op_sel:[1,0,0] op_sel_hi:[1,0,0]\n\t"
        "v_fma_mix_f32 %4, %10, %12, %4 op_sel:[0,0,0] op_sel_hi:[1,0,0]\n\t"
        "v_fma_mix_f32 %5, %10, %12, %5 op_sel:[1,0,0] op_sel_hi:[1,0,0]\n\t"
        "v_fma_mix_f32 %6, %11, %12, %6 op_sel:[0,0,0] op_sel_hi:[1,0,0]\n\t"
        "v_fma_mix_f32 %7, %11, %12, %7 op_sel:[1,0,0] op_sel_hi:[1,0,0]"
        : "+v"(a[0]), "+v"(a[1]), "+v"(a[2]), "+v"(a[3]),
          "+v"(a[4]), "+v"(a[5]), "+v"(a[6]), "+v"(a[7])
        : "v"(r.x), "v"(r.y), "v"(r.z), "v"(r.w), "v"(nm));
}

// ================= device bodies (shared by fused dispatches) =================

// ---- atom encoder + MFMA @ W0 for node block `encblk` (row-major hw out) ----
__device__ void enc_body(char* smem_raw, int tid, int encblk,
        const int* __restrict__ x, const float* __restrict__ emb,
        const unsigned short* __restrict__ WThi, const unsigned short* __restrict__ WTlo,
        __half* __restrict__ hw_out) {
    unsigned short (*lh)[136] = (unsigned short(*)[136])smem_raw;
    unsigned short (*ll)[136] = (unsigned short(*)[136])(smem_raw + 32 * 136 * 2);
    int nloc = tid >> 3;           // 0..31
    int seg = tid & 7;             // 16-ch segment
    int nodebase = encblk * 32;
    int n = nodebase + nloc;
    float s[16];
#pragma unroll
    for (int i = 0; i < 16; ++i) s[i] = 0.f;
#pragma unroll
    for (int f = 0; f < NF; ++f) {
        int idx = x[n * NF + f];
        const float4* ep = (const float4*)(emb + ((size_t)(f * VV + idx)) * HH + seg * 16);
#pragma unroll
        for (int q = 0; q < 4; ++q) {
            float4 e = ep[q];
            s[q * 4 + 0] += e.x; s[q * 4 + 1] += e.y;
            s[q * 4 + 2] += e.z; s[q * 4 + 3] += e.w;
        }
    }
#pragma unroll
    for (int q = 0; q < 4; ++q) {
        ushort4 oh, ol;
        oh.x = f2bf(s[q * 4 + 0]); ol.x = f2bf(s[q * 4 + 0] - bf2f(oh.x));
        oh.y = f2bf(s[q * 4 + 1]); ol.y = f2bf(s[q * 4 + 1] - bf2f(oh.y));
        oh.z = f2bf(s[q * 4 + 2]); ol.z = f2bf(s[q * 4 + 2] - bf2f(oh.z));
        oh.w = f2bf(s[q * 4 + 3]); ol.w = f2bf(s[q * 4 + 3] - bf2f(oh.w));
        *(ushort4*)&lh[nloc][seg * 16 + q * 4] = oh;
        *(ushort4*)&ll[nloc][seg * 16 + q * 4] = ol;
    }
    __syncthreads();
    int wave = tid >> 6, lane = tid & 63;
    int quad = lane >> 4, m = lane & 15;
    f32x4 acc[2][2] = {};
    int kq = quad * 8;
#pragma unroll
    for (int t = 0; t < 4; ++t) {
        int k0 = t * 32 + kq;
        short8 a0h = *(const short8*)&lh[m][k0];
        short8 a0l = *(const short8*)&ll[m][k0];
        short8 a1h = *(const short8*)&lh[16 + m][k0];
        short8 a1l = *(const short8*)&ll[16 + m][k0];
#pragma unroll
        for (int c = 0; c < 2; ++c) {
            int ct = wave * 2 + c;
            short8 bh = *(const short8*)(WThi + (size_t)(ct * 16 + m) * HH + k0);
            short8 bl = *(const short8*)(WTlo + (size_t)(ct * 16 + m) * HH + k0);
            acc[0][c] = __builtin_amdgcn_mfma_f32_16x16x32_bf16(a0h, bh, acc[0][c], 0, 0, 0);
            acc[0][c] = __builtin_amdgcn_mfma_f32_16x16x32_bf16(a0l, bh, acc[0][c], 0, 0, 0);
            acc[0][c] = __builtin_amdgcn_mfma_f32_16x16x32_bf16(a0h, bl, acc[0][c], 0, 0, 0);
            acc[1][c] = __builtin_amdgcn_mfma_f32_16x16x32_bf16(a1h, bh, acc[1][c], 0, 0, 0);
            acc[1][c] = __builtin_amdgcn_mfma_f32_16x16x32_bf16(a1l, bh, acc[1][c], 0, 0, 0);
            acc[1][c] = __builtin_amdgcn_mfma_f32_16x16x32_bf16(a1h, bl, acc[1][c], 0, 0, 0);
        }
    }
#pragma unroll
    for (int c = 0; c < 2; ++c) {
        int colx = (wave * 2 + c) * 16 + m;
#pragma unroll
        for (int rt = 0; rt < 2; ++rt) {
            int r0 = nodebase + rt * 16 + quad * 4;
#pragma unroll
            for (int reg = 0; reg < 4; ++reg)
                hw_out[(size_t)(r0 + reg) * HH + colx] = __float2half(acc[rt][c][reg]);
        }
    }
}

// ================= CSR-chain kernels, each carrying a slab of enc blocks =====

__global__ __launch_bounds__(256) void split_enc_kernel(
        const int* __restrict__ src, const int* __restrict__ dst,
        int* __restrict__ bcur, int* __restrict__ bucket_edges,
        const int* __restrict__ x, const float* __restrict__ emb,
        const unsigned short* __restrict__ WThi, const unsigned short* __restrict__ WTlo,
        __half* __restrict__ hw_out) {
    __shared__ __align__(16) char smem_raw[25600];
    int tid = threadIdx.x;
    if (blockIdx.x >= NSPLIT) {
        enc_body(smem_raw, tid, blockIdx.x - NSPLIT, x, emb, WThi, WTlo, hw_out);
        return;
    }
    int* lcnt  = (int*)smem_raw;
    int* loff  = lcnt + 256;
    int* lcur  = loff + 256;
    int* gbase = lcur + 256;
    int* sh    = gbase + 256;
    int* stage = sh + 256;
    unsigned char* stageb = (unsigned char*)(stage + CHUNK);
    int cs = blockIdx.x * CHUNK;
    int n = min(CHUNK, EE - cs);
    lcnt[tid] = 0;
    __syncthreads();
    for (int i = tid; i < n; i += 256)
        atomicAdd(&lcnt[dst[cs + i] >> 9], 1);
    __syncthreads();
    int val = lcnt[tid];
    sh[tid] = val; __syncthreads();
    for (int d = 1; d < 256; d <<= 1) {
        int t = (tid >= d) ? sh[tid - d] : 0;
        __syncthreads();
        sh[tid] += t;
        __syncthreads();
    }
    loff[tid] = sh[tid] - val;
    lcur[tid] = sh[tid] - val;
    __syncthreads();
    for (int i = tid; i < n; i += 256) {
        int d = dst[cs + i], s = src[cs + i];
        int b = d >> 9;
        int p = atomicAdd(&lcur[b], 1);
        stage[p] = (s << 9) | (d & 511);
        stageb[p] = (unsigned char)b;
    }
    if (val > 0) gbase[tid] = atomicAdd(&bcur[tid], val);
    __syncthreads();
    for (int i = tid; i < n; i += 256) {
        int b = stageb[i];
        bucket_edges[(size_t)b * BCAP + gbase[b] + (i - loff[b])] = stage[i];
    }
}

__global__ __launch_bounds__(256) void bhist_enc_kernel(const int* __restrict__ bcur,
        const int* __restrict__ bucket_edges,
        int* __restrict__ cnt, float* __restrict__ dinv, int* __restrict__ bsum,
        const int* __restrict__ x, const float* __restrict__ emb,
        const unsigned short* __restrict__ WThi, const unsigned short* __restrict__ WTlo,
        __half* __restrict__ hw_out) {
    __shared__ __align__(16) char smem_raw[17408];
    int tid = threadIdx.x;
    if (blockIdx.x >= NBUCK) {
        enc_body(smem_raw, tid, EN1 + (blockIdx.x - NBUCK), x, emb, WThi, WTlo, hw_out);
        return;
    }
    int* lc = (int*)smem_raw;          // 512 ints
    int* sh = lc + 512;                // 256 ints
    int b = blockIdx.x;
    lc[tid] = 0; lc[tid + 256] = 0;
    __syncthreads();
    int n = bcur[b];
    const int* be = bucket_edges + (size_t)b * BCAP;
    for (int i = tid; i < n; i += 256) atomicAdd(&lc[be[i] & 511], 1);
    __syncthreads();
    int node = b * 512 + tid;
    int c0 = lc[tid], c1 = lc[tid + 256];
    int s = 0;
    if (node < NN) { cnt[node] = c0; dinv[node] = rsqrtf(1.0f + (float)c0); s += c0; }
    if (node + 256 < NN) { cnt[node + 256] = c1; dinv[node + 256] = rsqrtf(1.0f + (float)c1); s += c1; }
    sh[tid] = s; __syncthreads();
    for (int d = 128; d > 0; d >>= 1) { if (tid < d) sh[tid] += sh[tid + d]; __syncthreads(); }
    if (tid == 0) bsum[b] = sh[0];
}

// ---- merged node-scan + CSR scatter: block b serves bucket b end-to-end ----
__global__ __launch_bounds__(256) void scan_scatter_enc_kernel(const int* __restrict__ cnt,
        const int* __restrict__ bsum, int* __restrict__ row_ptr,
        const int* __restrict__ bcur, const int* __restrict__ bucket_edges,
        const float* __restrict__ dinv, int2* __restrict__ col,
        const int* __restrict__ x, const float* __restrict__ emb,
        const unsigned short* __restrict__ WThi, const unsigned short* __restrict__ WTlo,
        __half* __restrict__ hw_out) {
    __shared__ __align__(16) char smem_raw[17408];
    int tid = threadIdx.x;
    if (blockIdx.x >= NBUCK) {
        enc_body(smem_raw, tid, EN1 + EN2 + (blockIdx.x - NBUCK), x, emb, WThi, WTlo, hw_out);
        return;
    }
    int* sh   = (int*)smem_raw;        // 256 ints
    int* pre  = sh + 256;              // 256 ints
    int* lcur = pre + 256;             // 512 ints
    int b = blockIdx.x;
    pre[tid] = (tid < b) ? bsum[tid] : 0;   // b <= 195 < 256
    __syncthreads();
    for (int d = 128; d > 0; d >>= 1) { if (tid < d) pre[tid] += pre[tid + d]; __syncthreads(); }
    int bbase = pre[0];
    int base = b * 512 + tid * 2;
    int v0 = (base < NN) ? cnt[base] : 0;
    int v1 = (base + 1 < NN) ? cnt[base + 1] : 0;
    int ts = v0 + v1;
    sh[tid] = ts; __syncthreads();
    for (int d = 1; d < 256; d <<= 1) {
        int t = (tid >= d) ? sh[tid - d] : 0;
        __syncthreads();
        sh[tid] += t;
        __syncthreads();
    }
    int excl = sh[tid] - ts + bbase;
    if (base < NN) row_ptr[base] = excl;
    if (base + 1 < NN) row_ptr[base + 1] = excl + v0;
    lcur[tid * 2] = excl;
    lcur[tid * 2 + 1] = excl + v0;
    if (b == 0 && tid == 0) row_ptr[NN] = EE;
    __syncthreads();
    // scatter
    int node0 = b * 512;
    int n = bcur[b];
    const int* be = bucket_edges + (size_t)b * BCAP;
    for (int i = tid; i < n; i += 256) {
        int w = be[i];
        int j = w & 511;
        int s = (int)((unsigned)w >> 9);
        int p = atomicAdd(&lcur[j], 1);
        float nm = dinv[s] * dinv[node0 + j];
        col[p] = make_int2(s, __float_as_int(nm));
    }
}

// ---------------- W^T conversion + classifier prep + clears + graph counts ----------------
__global__ __launch_bounds__(256) void wprep_kernel(const float* __restrict__ Ws,
        const float* __restrict__ Wc, const float* __restrict__ b2,
        const int* __restrict__ batch,
        unsigned short* __restrict__ WThi, unsigned short* __restrict__ WTlo,
        unsigned short* __restrict__ WcThi, unsigned short* __restrict__ WcTlo,
        float* __restrict__ bb2, int* __restrict__ bcur, float* __restrict__ pooled,
        int* __restrict__ gcnt) {
    int id = blockIdx.x * 256 + threadIdx.x;
    if (id < LL * HH * HH) {
        int layer = id >> 14;
        int rem = id & (HH * HH - 1);
        int k = rem >> 7, n = rem & 127;
        float w = Ws[id];
        unsigned short hi = f2bf(w);
        float lo = w - bf2f(hi);
        WThi[(size_t)layer * HH * HH + n * HH + k] = hi;   // transposed: [n][k]
        WTlo[(size_t)layer * HH * HH + n * HH + k] = f2bf(lo);
    }
    int tid = threadIdx.x;
    if (blockIdx.x == 0) {
        const float* W2 = Ws + (size_t)2 * HH * HH;        // layer-2 weight [k][j]
        for (int i = tid; i < 16 * HH; i += 256) {
            int n = i >> 7, k = i & 127;
            float s = 0.f;
            if (n < OUTD) {
                for (int j = 0; j < HH; ++j)
                    s += W2[k * HH + j] * Wc[j * OUTD + n];   // Wfused[k][n]
            }
            unsigned short hi = f2bf(s);
            WcThi[i] = hi;                 // [n][k] transposed
            WcTlo[i] = f2bf(s - bf2f(hi));
        }
        if (tid < OUTD) {
            float s = 0.f;
            for (int c = 0; c < HH; ++c) s += b2[c] * Wc[c * OUTD + tid];
            bb2[tid] = s;
        }
    } else if (blockIdx.x == 1) {
        bcur[tid] = 0;
    } else if (blockIdx.x >= 2 && blockIdx.x < 66) {
        pooled[(blockIdx.x - 2) * 256 + tid] = 0.f;        // GG*16 = 64*256
    } else if (blockIdx.x >= 66 && blockIdx.x < 70) {
        int g = (blockIdx.x - 66) * 256 + tid;             // 0..1023
        int lo = 0, hi = NN;
        while (lo < hi) { int mid = (lo + hi) >> 1; if (batch[mid] < g) lo = mid + 1; else hi = mid; }
        int s0 = lo;
        lo = 0; hi = NN;
        int g1 = g + 1;
        while (lo < hi) { int mid = (lo + hi) >> 1; if (batch[mid] < g1) lo = mid + 1; else hi = mid; }
        gcnt[g] = lo - s0;
    }
}

// ---------------- Gather core: one 16-lane group per node (128-ch rows) ----------------
__device__ inline void gather_node(const uint4* __restrict__ hw4,
                                   const int2* __restrict__ col,
                                   int start, int end, int c4,
                                   float a[8], float b[8]) {
    int e = start;
    for (; e + 4 <= end; e += 4) {
        unsigned long long w0 = *(const unsigned long long*)&col[e];
        unsigned long long w1 = *(const unsigned long long*)&col[e + 1];
        unsigned long long w2 = *(const unsigned long long*)&col[e + 2];
        unsigned long long w3 = *(const unsigned long long*)&col[e + 3];
        uint4 r0 = hw4[(size_t)(unsigned)(w0 & 0xffffffffu) * 16 + c4];
        uint4 r1 = hw4[(size_t)(unsigned)(w1 & 0xffffffffu) * 16 + c4];
        uint4 r2 = hw4[(size_t)(unsigned)(w2 & 0xffffffffu) * 16 + c4];
        uint4 r3 = hw4[(size_t)(unsigned)(w3 & 0xffffffffu) * 16 + c4];
        mix8(a, r0, __int_as_float((int)(unsigned)(w0 >> 32)));
        mix8(b, r1, __int_as_float((int)(unsigned)(w1 >> 32)));
        mix8(a, r2, __int_as_float((int)(unsigned)(w2 >> 32)));
        mix8(b, r3, __int_as_float((int)(unsigned)(w3 >> 32)));
    }
    if (e < end) {
        int last = end - 1;
        int e1 = min(e + 1, last), e2 = min(e + 2, last), e3 = min(e + 3, last);
        unsigned long long w0 = *(const unsigned long long*)&col[e];
        unsigned long long w1 = *(const unsigned long long*)&col[e1];
        unsigned long long w2 = *(const unsigned long long*)&col[e2];
        unsigned long long w3 = *(const unsigned long long*)&col[e3];
        float n0 = __int_as_float((int)(unsigned)(w0 >> 32));
        float n1 = (e + 1 < end) ? __int_as_float((int)(unsigned)(w1 >> 32)) : 0.f;
        float n2 = (e + 2 < end) ? __int_as_float((int)(unsigned)(w2 >> 32)) : 0.f;
        float n3 = (e + 3 < end) ? __int_as_float((int)(unsigned)(w3 >> 32)) : 0.f;
        uint4 r0 = hw4[(size_t)(unsigned)(w0 & 0xffffffffu) * 16 + c4];
        uint4 r1 = hw4[(size_t)(unsigned)(w1 & 0xffffffffu) * 16 + c4];
        uint4 r2 = hw4[(size_t)(unsigned)(w2 & 0xffffffffu) * 16 + c4];
        uint4 r3 = hw4[(size_t)(unsigned)(w3 & 0xffffffffu) * 16 + c4];
        mix8(a, r0, n0);
        mix8(b, r1, n1);
        mix8(a, r2, n2);
        mix8(b, r3, n3);
    }
}

// ---------------- Fused: CSR aggregate + bias + BN + ReLU -> LDS -> MFMA ----------------
template<bool DO_PROJ>
__global__ __launch_bounds__(512) void agg_mm_kernel(const __half* __restrict__ hw_in,
    const int* __restrict__ row_ptr, const int2* __restrict__ col,
    const float* __restrict__ dinv,
    const float* __restrict__ bias, const float* __restrict__ gamma,
    const float* __restrict__ beta, const float* __restrict__ rmean,
    const float* __restrict__ rvar,
    const unsigned short* __restrict__ WThi, const unsigned short* __restrict__ WTlo,
    __half* __restrict__ hw_out,
    const unsigned short* __restrict__ WcThi, const unsigned short* __restrict__ WcTlo,
    __half* __restrict__ y_out) {
    __shared__ __align__(16) unsigned short lh[32][136];
    __shared__ __align__(16) unsigned short ll[32][136];
    int wave = threadIdx.x >> 6;     // 0..7
    int lane = threadIdx.x & 63;
    int grp = lane >> 4;             // 0..3 : node within wave
    int c4 = lane & 15;              // 16B chunk within row
    int nodebase = blockIdx.x * 32;
    const uint4* hw4 = (const uint4*)hw_in;

    int v = nodebase + wave * 4 + grp;
    int start = row_ptr[v], end = row_ptr[v + 1];
    float a[8] = {}, b[8] = {};
    gather_node(hw4, col, start, end, c4, a, b);

    // self-loop term
    {
        float dv = dinv[v];
        uint4 r = hw4[(size_t)v * 16 + c4];
        mix8(a, r, dv * dv);
    }
#pragma unroll
    for (int i = 0; i < 8; ++i) a[i] += b[i];

    int ch = c4 * 8;
#pragma unroll
    for (int i = 0; i < 8; ++i) a[i] += bias[ch + i];
#pragma unroll
    for (int i = 0; i < 8; ++i) {
        int c = ch + i;
        float sc = gamma[c] * rsqrtf(rvar[c] + BN_EPS);
        a[i] = fmaxf((a[i] - rmean[c]) * sc + beta[c], 0.f);
    }
    int rloc = wave * 4 + grp;
    ushort4 oh0, oh1, ol0, ol1;
    oh0.x = f2bf(a[0]); ol0.x = f2bf(a[0] - bf2f(oh0.x));
    oh0.y = f2bf(a[1]); ol0.y = f2bf(a[1] - bf2f(oh0.y));
    oh0.z = f2bf(a[2]); ol0.z = f2bf(a[2] - bf2f(oh0.z));
    oh0.w = f2bf(a[3]); ol0.w = f2bf(a[3] - bf2f(oh0.w));
    oh1.x = f2bf(a[4]); ol1.x = f2bf(a[4] - bf2f(oh1.x));
    oh1.y = f2bf(a[5]); ol1.y = f2bf(a[5] - bf2f(oh1.y));
    oh1.z = f2bf(a[6]); ol1.z = f2bf(a[6] - bf2f(oh1.z));
    oh1.w = f2bf(a[7]); ol1.w = f2bf(a[7] - bf2f(oh1.w));
    *(ushort4*)&lh[rloc][ch]     = oh0;
    *(ushort4*)&lh[rloc][ch + 4] = oh1;
    *(ushort4*)&ll[rloc][ch]     = ol0;
    *(ushort4*)&ll[rloc][ch + 4] = ol1;

    __syncthreads();
    int quad = lane >> 4, m = lane & 15;
    int kq = quad * 8;
    if constexpr (!DO_PROJ) {
        f32x4 acc[2] = {};
        int ct = wave;                   // 1 column-tile per wave
#pragma unroll
        for (int t = 0; t < 4; ++t) {
            int k0 = t * 32 + kq;
            short8 a0h = *(const short8*)&lh[m][k0];
            short8 a0l = *(const short8*)&ll[m][k0];
            short8 a1h = *(const short8*)&lh[16 + m][k0];
            short8 a1l = *(const short8*)&ll[16 + m][k0];
            short8 bh = *(const short8*)(WThi + (size_t)(ct * 16 + m) * HH + k0);
            short8 bl = *(const short8*)(WTlo + (size_t)(ct * 16 + m) * HH + k0);
            acc[0] = __builtin_amdgcn_mfma_f32_16x16x32_bf16(a0h, bh, acc[0], 0, 0, 0);
            acc[0] = __builtin_amdgcn_mfma_f32_16x16x32_bf16(a0l, bh, acc[0], 0, 0, 0);
            acc[0] = __builtin_amdgcn_mfma_f32_16x16x32_bf16(a0h, bl, acc[0], 0, 0, 0);
            acc[1] = __builtin_amdgcn_mfma_f32_16x16x32_bf16(a1h, bh, acc[1], 0, 0, 0);
            acc[1] = __builtin_amdgcn_mfma_f32_16x16x32_bf16(a1l, bh, acc[1], 0, 0, 0);
            acc[1] = __builtin_amdgcn_mfma_f32_16x16x32_bf16(a1h, bl, acc[1], 0, 0, 0);
        }
        int colx = ct * 16 + m;
#pragma unroll
        for (int rt = 0; rt < 2; ++rt) {
            int r0 = nodebase + rt * 16 + quad * 4;
#pragma unroll
            for (int reg = 0; reg < 4; ++reg)
                hw_out[(size_t)(r0 + reg) * HH + colx] = __float2half(acc[rt][reg]);
        }
    } else {
        // y = h2_rows @ Wfused^T : waves 0,1 handle row-tiles 0,1; cols 0-15
        if (wave < 2) {
            f32x4 pacc = {};
#pragma unroll
            for (int t = 0; t < 4; ++t) {
                int k0 = t * 32 + kq;
                short8 ah = *(const short8*)&lh[wave * 16 + m][k0];
                short8 al = *(const short8*)&ll[wave * 16 + m][k0];
                short8 bh = *(const short8*)(WcThi + (size_t)m * HH + k0);
                short8 bl = *(const short8*)(WcTlo + (size_t)m * HH + k0);
                pacc = __builtin_amdgcn_mfma_f32_16x16x32_bf16(ah, bh, pacc, 0, 0, 0);
                pacc = __builtin_amdgcn_mfma_f32_16x16x32_bf16(al, bh, pacc, 0, 0, 0);
                pacc = __builtin_amdgcn_mfma_f32_16x16x32_bf16(ah, bl, pacc, 0, 0, 0);
            }
#pragma unroll
            for (int reg = 0; reg < 4; ++reg) {
                int node = nodebase + wave * 16 + quad * 4 + reg;
                y_out[(size_t)node * 16 + m] = __float2half(pacc[reg]);
            }
        }
    }
}

// ---------------- Last aggregate on 16-ch f16 y + per-graph pooling partials ----------------
__global__ __launch_bounds__(256) void agg_pool_kernel(const __half* __restrict__ y,
    const int* __restrict__ row_ptr, const int2* __restrict__ col,
    const float* __restrict__ dinv, const int* __restrict__ batch,
    float* __restrict__ pooled) {
    __shared__ __align__(16) float lz[128][16];
    __shared__ int bg[128];
    int tid = threadIdx.x;
    int g2 = tid >> 1;               // node slot 0..127
    int cl = tid & 1;                // 16B half of row
    int nodebase = blockIdx.x * 128;
    int v = nodebase + g2;
    int vc = min(v, NN - 1);
    int start = row_ptr[vc];
    int end = (v < NN) ? row_ptr[vc + 1] : start;
    const uint4* y4 = (const uint4*)y;   // row = 2 x uint4 (16 halves)
    float a[8] = {};
    int e = start;
    for (; e + 4 <= end; e += 4) {
        unsigned long long w0 = *(const unsigned long long*)&col[e];
        unsigned long long w1 = *(const unsigned long long*)&col[e + 1];
        unsigned long long w2 = *(const unsigned long long*)&col[e + 2];
        unsigned long long w3 = *(const unsigned long long*)&col[e + 3];
        uint4 r0 = y4[(size_t)(unsigned)(w0 & 0xffffffffu) * 2 + cl];
        uint4 r1 = y4[(size_t)(unsigned)(w1 & 0xffffffffu) * 2 + cl];
        uint4 r2 = y4[(size_t)(unsigned)(w2 & 0xffffffffu) * 2 + cl];
        uint4 r3 = y4[(size_t)(unsigned)(w3 & 0xffffffffu) * 2 + cl];
        mix8(a, r0, __int_as_float((int)(unsigned)(w0 >> 32)));
        mix8(a, r1, __int_as_float((int)(unsigned)(w1 >> 32)));
        mix8(a, r2, __int_as_float((int)(unsigned)(w2 >> 32)));
        mix8(a, r3, __int_as_float((int)(unsigned)(w3 >> 32)));
    }
    if (e < end) {
        int last = end - 1;
        int e1 = min(e + 1, last), e2 = min(e + 2, last), e3 = min(e + 3, last);
        unsigned long long w0 = *(const unsigned long long*)&col[e];
        unsigned long long w1 = *(const unsigned long long*)&col[e1];
        unsigned long long w2 = *(const unsigned long long*)&col[e2];
        unsigned long long w3 = *(const unsigned long long*)&col[e3];
        float n0 = __int_as_float((int)(unsigned)(w0 >> 32));
        float n1 = (e + 1 < end) ? __int_as_float((int)(unsigned)(w1 >> 32)) : 0.f;
        float n2 = (e + 2 < end) ? __int_as_float((int)(unsigned)(w2 >> 32)) : 0.f;
        float n3 = (e + 3 < end) ? __int_as_float((int)(unsigned)(w3 >> 32)) : 0.f;
        uint4 r0 = y4[(size_t)(unsigned)(w0 & 0xffffffffu) * 2 + cl];
        uint4 r1 = y4[(size_t)(unsigned)(w1 & 0xffffffffu) * 2 + cl];
        uint4 r2 = y4[(size_t)(unsigned)(w2 & 0xffffffffu) * 2 + cl];
        uint4 r3 = y4[(size_t)(unsigned)(w3 & 0xffffffffu) * 2 + cl];
        mix8(a, r0, n0);
        mix8(a, r1, n1);
        mix8(a, r2, n2);
        mix8(a, r3, n3);
    }
    if (v < NN) {
        float dv = dinv[v];
        uint4 r = y4[(size_t)v * 2 + cl];
        mix8(a, r, dv * dv);
    } else {
#pragma unroll
        for (int i = 0; i < 8; ++i) a[i] = 0.f;
    }
    int chb = cl * 8;
#pragma unroll
    for (int i = 0; i < 8; ++i) lz[g2][chb + i] = a[i];
    if (cl == 0) bg[g2] = batch[vc];
    __syncthreads();
    // pooling partials: 256 threads = 16 ch x 16 row-groups of 8
    int ch = tid & 15;
    int rh = tid >> 4;               // 0..15
    int r0i = rh * 8;
    int curg = bg[r0i];
    float run = 0.f;
    for (int r = r0i; r < r0i + 8; ++r) {
        int gg = bg[r];
        if (gg != curg) {
            atomicAdd(&pooled[(size_t)curg * 16 + ch], run);
            run = 0.f; curg = gg;
        }
        run += lz[r][ch];
    }
    atomicAdd(&pooled[(size_t)curg * 16 + ch], run);
}

// ---------------- mean + bias fold (gcnt precomputed in wprep) ----------------
__global__ __launch_bounds__(256) void finalize_kernel(const float* __restrict__ pooled,
    const int* __restrict__ gcnt, const float* __restrict__ bb2,
    const float* __restrict__ bc, float* __restrict__ out) {
    int id = blockIdx.x * 256 + threadIdx.x;
    if (id >= GG * OUTD) return;
    int g = id / OUTD, o = id - g * OUTD;
    int cg = gcnt[g];
    float r = pooled[(size_t)g * 16 + o] / fmaxf((float)cg, 1.0f);
    out[(size_t)g * OUTD + o] = r + ((cg > 0) ? bb2[o] : 0.f) + bc[o];
}

extern "C" void kernel_launch(void* const* d_in, const int* in_sizes, int n_in,
                              void* d_out, int out_size, void* d_ws, size_t ws_size,
                              hipStream_t stream) {
    const int*   x      = (const int*)d_in[0];
    const int*   eidx   = (const int*)d_in[1];
    const int*   batch  = (const int*)d_in[2];
    const float* emb    = (const float*)d_in[3];
    const float* Ws     = (const float*)d_in[4];
    const float* bs     = (const float*)d_in[5];
    const float* gamma  = (const float*)d_in[6];
    const float* beta   = (const float*)d_in[7];
    const float* rmean  = (const float*)d_in[8];
    const float* rvar   = (const float*)d_in[9];
    const float* Wclf   = (const float*)d_in[10];
    const float* bclf   = (const float*)d_in[11];
    float* out = (float*)d_out;

    const int* e_src = eidx;
    const int* e_dst = eidx + EE;

    char* ws = (char*)d_ws;
    size_t off = 0;
    auto take = [&](size_t bytes) -> void* {
        void* p = ws + off;
        off = (off + bytes + 255) & ~(size_t)255;
        return p;
    };
    float* dinv     = (float*)take((size_t)NN * 4);
    int*   cnt      = (int*)  take((size_t)NN * 4);
    int*   row_ptr  = (int*)  take((size_t)(NN + 1) * 4);
    int*   bsum     = (int*)  take((size_t)NBUCK * 4);
    int*   bcur     = (int*)  take((size_t)256 * 4);
    int*   gcnt     = (int*)  take((size_t)GG * 4);
    int*   bucket_edges = (int*)take((size_t)NBUCK * BCAP * 4);
    int2*  col      = (int2*) take((size_t)EE * 8 + 64);   // +64B safety pad
    __half* hwA     = (__half*)take((size_t)NN * HH * 2);
    __half* hwB     = (__half*)take((size_t)NN * HH * 2);
    __half* yh      = (__half*)take((size_t)NN * 16 * 2);
    float* pooled   = (float*)take((size_t)GG * 16 * 4);
    unsigned short* WThi = (unsigned short*)take((size_t)LL * HH * HH * 2);
    unsigned short* WTlo = (unsigned short*)take((size_t)LL * HH * HH * 2);
    unsigned short* WcThi = (unsigned short*)take((size_t)16 * HH * 2);
    unsigned short* WcTlo = (unsigned short*)take((size_t)16 * HH * 2);
    float* bb2      = (float*)take((size_t)16 * 4);

    // weight prep + buffer clears + graph counts
    wprep_kernel<<<(LL * HH * HH + 255) / 256, 256, 0, stream>>>(Ws, Wclf, bs + 2 * HH,
        batch, WThi, WTlo, WcThi, WcTlo, bb2, bcur, pooled, gcnt);
    // CSR chain with enc blocks spread across all three dispatches:
    split_enc_kernel<<<NSPLIT + EN1, 256, 0, stream>>>(e_src, e_dst, bcur, bucket_edges,
        x, emb, WThi, WTlo, hwA);
    bhist_enc_kernel<<<NBUCK + EN2, 256, 0, stream>>>(bcur, bucket_edges, cnt, dinv, bsum,
        x, emb, WThi, WTlo, hwA);
    scan_scatter_enc_kernel<<<NBUCK + EN3, 256, 0, stream>>>(cnt, bsum, row_ptr,
        bcur, bucket_edges, dinv, col,
        x, emb, WThi, WTlo, hwA);

    // layer 0: agg(hw1)+bias0+BN0+ReLU -> LDS -> @ W1 -> hw2
    agg_mm_kernel<false><<<NN / 32, 512, 0, stream>>>(hwA, row_ptr, col, dinv,
        bs, gamma, beta, rmean, rvar,
        WThi + (size_t)1 * HH * HH, WTlo + (size_t)1 * HH * HH, hwB,
        nullptr, nullptr, nullptr);
    // layer 1: agg(hw2)+bias1+BN1+ReLU -> y = h2 @ (W2@Wc) only
    agg_mm_kernel<true><<<NN / 32, 512, 0, stream>>>(hwB, row_ptr, col, dinv,
        bs + HH, gamma + HH, beta + HH, rmean + HH, rvar + HH,
        nullptr, nullptr, nullptr,
        WcThi, WcTlo, yh);
    // layer 2 aggregate on 16-ch f16 y + pooling partials
    agg_pool_kernel<<<NB128, 256, 0, stream>>>(yh, row_ptr, col, dinv, batch, pooled);
    // mean + fold b2@Wc + bc
    finalize_kernel<<<(GG * OUTD + 255) / 256, 256, 0, stream>>>(pooled, gcnt, bb2, bclf, out);
}